// Round 1
// baseline (380.883 us; speedup 1.0000x reference)
//
#include <hip/hip_runtime.h>
#include <math.h>

#define NBINS 16
#define BOUNDV 3.0f
#define MIN_W 0.001f
#define MIN_H 0.001f
#define MIN_D 0.001f
#define MIN_L 0.025f
#define EPSV 1e-6f

#define TPB 128          // threads per block = elements per block
#define PPE 63           // params per element (4*16-1)

__device__ __forceinline__ float softplusf(float v) {
    // log(1+exp(v)) = max(v,0) + log1p(exp(-|v|))
    return fmaxf(v, 0.f) + log1pf(__expf(-fabsf(v)));
}

__global__ __launch_bounds__(TPB) void lrs_kernel(
    const float* __restrict__ x_in,
    const float* __restrict__ params,
    float* __restrict__ out,
    int n)
{
    __shared__ float lds[TPB * PPE];   // 32,256 B -> 5 blocks/CU
    const int tid = threadIdx.x;
    const int gid = blockIdx.x * TPB + tid;

    // ---- stage this block's param slab (contiguous, 16B-aligned) ----
    {
        const float4* __restrict__ src =
            (const float4*)(params + (size_t)blockIdx.x * (TPB * PPE));
        float4* dst = (float4*)lds;
        const int nvec = TPB * PPE / 4;   // 2016
        for (int j = tid; j < nvec; j += TPB) {
            dst[j] = src[j];
        }
    }
    __syncthreads();

    const float x = x_in[gid];
    const float* __restrict__ p = lds + tid * PPE;  // stride 63: odd -> bank-conflict-free

    // ---- softmax over w (params 0..15) ----
    float wv[NBINS];
    float mw = -1e30f;
    #pragma unroll
    for (int i = 0; i < NBINS; ++i) { wv[i] = p[i]; mw = fmaxf(mw, wv[i]); }
    float sw = 0.f;
    #pragma unroll
    for (int i = 0; i < NBINS; ++i) { wv[i] = __expf(wv[i] - mw); sw += wv[i]; }
    const float invw = 1.f / sw;

    // ---- width knots: fused cumsum + bin search + knot selection ----
    // knots[0] = -3; knots[i] = -3 + 6*cumsum(widths)[i]; knots[16] forced to +3
    // bin = clip(count(knots+eps <= x) - 1, 0, 15)
    float cum = 0.f;
    float knp = -BOUNDV;          // knot[i] at iteration i
    int   bin = 0;
    float cw  = -BOUNDV;          // cumwidths[bin]
    float cwn = 0.f;              // cumwidths[bin+1]
    #pragma unroll
    for (int i = 0; i < NBINS; ++i) {
        cum += fmaf(0.984f, wv[i] * invw, MIN_W);            // width_i
        float kn = (i == NBINS - 1) ? BOUNDV : fmaf(6.f, cum, -BOUNDV);  // knot[i+1]
        bool hit = (knp + EPSV <= x);
        if (i == 0) { cwn = kn; }                            // defaults (bin 0)
        else if (hit) { bin = i; cw = knp; cwn = kn; }
        knp = kn;
    }

    // ---- softmax over h (params 16..31) ----
    float hv[NBINS];
    float mh = -1e30f;
    #pragma unroll
    for (int i = 0; i < NBINS; ++i) { hv[i] = p[16 + i]; mh = fmaxf(mh, hv[i]); }
    float sh = 0.f;
    #pragma unroll
    for (int i = 0; i < NBINS; ++i) { hv[i] = __expf(hv[i] - mh); sh += hv[i]; }
    const float invh = 1.f / sh;

    // ---- height knots: select knots[bin], knots[bin+1] ----
    float cumh = 0.f;
    float khp = -BOUNDV;
    float ya = -BOUNDV;           // cumheights[bin]
    float yb = 0.f;               // cumheights[bin+1] = heights[bin] + cumheights[bin]
    #pragma unroll
    for (int i = 0; i < NBINS; ++i) {
        cumh += fmaf(0.984f, hv[i] * invh, MIN_H);
        float kh = (i == NBINS - 1) ? BOUNDV : fmaf(6.f, cumh, -BOUNDV);
        if (i == bin) { ya = khp; yb = kh; }
        khp = kh;
    }

    // ---- derivatives: only the two selected ones (edges are constant) ----
    // derivs[0]=derivs[16]=1-MIN_D; derivs[k]=MIN_D+softplus(raw[k-1]) for k=1..15
    const float draw_lo = p[32 + bin - 1];   // in-bounds LDS read even for bin==0 (unused then)
    const float draw_hi = p[32 + bin];       // unused when bin==15
    const float d_k  = (bin == 0)         ? (1.f - MIN_D) : (MIN_D + softplusf(draw_lo));
    const float d_k1 = (bin == NBINS - 1) ? (1.f - MIN_D) : (MIN_D + softplusf(draw_hi));

    // ---- lambda: only the selected one ----
    const float lraw = p[47 + bin];
    const float sig  = 1.f / (1.f + __expf(-lraw));
    const float lam  = fmaf(1.f - 2.f * MIN_L, sig, MIN_L);  // 0.95*sig + 0.025

    // ---- rational spline ----
    const float width  = cwn - cw;
    const float height = yb - ya;
    const float delta  = height / width;

    const float wb  = sqrtf(d_k / d_k1);
    const float lwb = lam * wb;
    const float wc  = (lam * d_k + (wb - lwb) * d_k1) / delta;
    const float l1  = 1.f - lam;
    const float yc  = (lwb * yb + l1 * ya) / (l1 + lwb);

    const float theta = (x - cw) / width;
    const bool  ind   = (theta <= lam);
    const float lt    = lam - theta;

    const float wcyc  = wc * yc;
    const float wcyct = wcyc * theta;
    const float num   = ind ? fmaf(ya, lt, wcyct)
                            : (wcyc - wcyct) - (wb * yb) * lt;
    const float wct   = wc * theta;
    const float den   = ind ? (wct + lt)
                            : (wc - wct) - wb * lt;
    float outv = num / den;

    const float dnum = wc * (ind ? lam * (yc - ya) : (wb - lwb) * (yb - yc)) / width;
    float lad = __logf(dnum) - 2.f * __logf(fabsf(den));

    const bool outside = (x < -BOUNDV) | (x > BOUNDV);
    outv = outside ? x   : outv;
    lad  = outside ? 0.f : lad;

    out[gid]     = outv;
    out[n + gid] = lad;
}

extern "C" void kernel_launch(void* const* d_in, const int* in_sizes, int n_in,
                              void* d_out, int out_size, void* d_ws, size_t ws_size,
                              hipStream_t stream) {
    const float* x      = (const float*)d_in[0];
    const float* params = (const float*)d_in[1];
    float* out          = (float*)d_out;
    const int n = in_sizes[0];            // 16384*64 = 1,048,576 (divisible by TPB)
    const int blocks = n / TPB;           // 8192
    lrs_kernel<<<blocks, TPB, 0, stream>>>(x, params, out, n);
}